// Round 5
// baseline (215.763 us; speedup 1.0000x reference)
//
#include <hip/hip_runtime.h>
#include <hip/hip_bf16.h>

// LocalCorrelation via MFMA, round 5: counted-vmcnt quarter pipeline.
// out[b, di*13+dj, h, w] = (1/16) * sum_c zt[b,c,h,w] * zt1[b,c,h+di-6,w+dj-6]
// B=8 C=256 H=W=128, 13x13 taps, zero-padded.
//
// Structure: block = 8h x 16w p-tile, 1024 thr = 16 waves (8 p-patches x 2
// q-halves), mfma_f32_16x16x32_bf16 (M=16 p-pixels, N=16 q-pixels, K=32ch).
// Staging: zt1 in 8-channel "quarters" via global_load_lds into a ring of 4
// raw LDS slots (20KB each); quarter q+3 issued while q is packed -> loads
// fly ~3 sub-phases; waits are counted (vmcnt(4), tail 2/0), fused with
// s_barrier in one asm block (memory clobber = fence both sides).
// PACK: 560 thr, 8 b32 reads + 4 cvt_pk + 1 b128 write, no masks (OOB units
// redirected to a zeroed 1KB page in d_ws at load time; 16B units are always
// fully valid or fully invalid). Frag: bf16 pixel-major, XOR oct swizzle,
// double-buffered (2x35KB). zt (A-operand) loaded global->reg once at start
// (before any GISSUE so vmcnt counts stay exact), packed to 32 VGPR bf16.
// MFMA geometry + epilogue carried verbatim from R2-R4 (verified).

#define HH 128
#define WW 128
#define CCT 256
#define NT 169
#define PW 16
#define QW 28
#define KHALF 85
#define OSTRIDE 132
#define RAWQ 20480               // bytes per raw quarter slot (1280 x 16B)
#define FRAGOFF 81920            // 4*RAWQ
#define FRAGSZ 35840             // 560 pixels * 64B
#define SMTOT (FRAGOFF + 2*FRAGSZ)   // 153600
#define CHPL (HH*WW)

typedef __attribute__((ext_vector_type(8))) short bf16x8;
typedef __attribute__((ext_vector_type(4))) float f32x4;

union SMEM { char raw[SMTOT]; float outb[KHALF*OSTRIDE]; };

static __device__ __forceinline__ unsigned pk2(float a, float b) {
    __hip_bfloat162 h = __float22bfloat162_rn(make_float2(a, b));
    union { __hip_bfloat162 h2; unsigned u; } c; c.h2 = h; return c.u;
}

__global__ void zero_ws(float* w) { if (threadIdx.x < 256) w[threadIdx.x] = 0.f; }

__global__ __launch_bounds__(1024)
void lc5(const float* __restrict__ zt, const float* __restrict__ zt1,
         const float* __restrict__ zpg, float* __restrict__ out) {
    __shared__ SMEM sm;
    char* smb = sm.raw;
    const int tid = threadIdx.x, lane = tid & 63, wid = tid >> 6;
    const int bid = blockIdx.x;
    const int b = bid & 7, t = bid >> 3;          // one batch per XCD
    const int h0 = (t >> 3) * 8, w0 = (t & 7) * PW;

    const int pw = wid & 7, qh = wid >> 3;
    const int py0 = (pw >> 2) * 4, px0w = (pw & 3) * 4;
    const int nlo = lane & 3, nhi = (lane >> 2) & 3, oo = lane >> 4;

    // ---- B gload descriptors (2 DMA insts/wave/quarter, uniform) ----
    const float* gp0; const float* gp1; int gadv0, gadv1;   // adv in floats
    {
        const int u = wid * 64 + lane;            // units 0..1023
        const int part = u & 7, tt = u >> 3;
        const int ch = tt / 20, qy = tt - ch * 20;
        const int gy = h0 + qy - 6, gxs = w0 - 8 + part * 4;
        const bool val = (gy >= 0) && (gy < HH) && (gxs >= 0) && (gxs <= WW - 4);
        gp0 = val ? zt1 + (((size_t)(b * CCT + ch) * HH + gy) * WW + gxs)
                  : zpg + (u & 63) * 4;
        gadv0 = val ? 8 * CHPL : 0;
    }
    {
        const int u = 1024 + wid * 16 + (lane & 15);   // units 1024..1279
        const int part = u & 7, tt = u >> 3;
        const int ch = tt / 20, qy = tt - ch * 20;
        const int gy = h0 + qy - 6, gxs = w0 - 8 + part * 4;
        const bool val = (gy >= 0) && (gy < HH) && (gxs >= 0) && (gxs <= WW - 4);
        gp1 = val ? zt1 + (((size_t)(b * CCT + ch) * HH + gy) * WW + gxs)
                  : zpg + (u & 63) * 4;
        gadv1 = val ? 8 * CHPL : 0;
    }

    // ---- PACK precompute (560 active: one q-pixel each) ----
    int rbyte = 0, fwb = 0, fxor = 0;
    if (tid < 560) {
        const int pqy = tid / 28, pqx = tid - pqy * 28;
        rbyte = (pqy * 32 + pqx + 2) * 4;         // raw row starts at gx=w0-8
        fwb = FRAGOFF + tid * 64;                 // pixel-major frag, fp = tid
        fxor = (pqx + pqy) & 3;
    }

    // ---- MFMA B-frag lane offsets (R2-verified geometry) ----
    int boff[8];
#pragma unroll
    for (int jj = 0; jj < 8; ++jj) {
        const int qi = qh * 8 + jj;
        const int qyL = py0 + (qi >> 2) * 4 + nhi;
        const int qxL = px0w + (qi & 3) * 4 + nlo;
        boff[jj] = FRAGOFF + (qyL * QW + qxL) * 64 + ((oo ^ ((qxL + qyL) & 3)) << 4);
    }

    // ---- A-operand: global->reg once, pack to bf16 (drained pre-GISSUE) ----
    bf16x8 abf[8];
    {
        const float* ap = zt + (((size_t)(b * CCT + oo * 8) * HH + (h0 + py0 + nhi)) * WW
                                + (w0 + px0w + nlo));
#pragma unroll
        for (int pr = 0; pr < 8; ++pr) {
            float a8[8];
#pragma unroll
            for (int e = 0; e < 8; ++e) a8[e] = ap[(size_t)(pr * 32 + e) * CHPL];
            union { unsigned u[4]; bf16x8 v; } au;
            au.u[0] = pk2(a8[0], a8[1]); au.u[1] = pk2(a8[2], a8[3]);
            au.u[2] = pk2(a8[4], a8[5]); au.u[3] = pk2(a8[6], a8[7]);
            abf[pr] = au.v;
        }
    }

#define GISSUE(SLOT) do {                                                      \
    __builtin_amdgcn_global_load_lds(                                          \
        (const __attribute__((address_space(1))) void*)gp0,                    \
        (__attribute__((address_space(3))) void*)(smb + (SLOT) * RAWQ + wid * 1024), \
        16, 0, 0);                                                             \
    gp0 += gadv0;                                                              \
    if (lane < 16)                                                             \
        __builtin_amdgcn_global_load_lds(                                      \
            (const __attribute__((address_space(1))) void*)gp1,                \
            (__attribute__((address_space(3))) void*)(smb + (SLOT) * RAWQ + 16384 + wid * 256), \
            16, 0, 0);                                                         \
    gp1 += gadv1;                                                              \
} while (0)

    f32x4 acc[8];
#pragma unroll
    for (int j = 0; j < 8; ++j) acc[j] = (f32x4){0.f, 0.f, 0.f, 0.f};

    // prologue: quarters 0,1,2 in flight
    GISSUE(0); GISSUE(1); GISSUE(2);

#pragma unroll
    for (int pr = 0; pr < 8; ++pr) {
#pragma unroll
        for (int sub = 0; sub < 4; ++sub) {
            const int q = 4 * pr + sub;
            // wait quarter q landed (2 insts/quarter; {q+1,q+2} stay in flight),
            // then barrier; fused in one asm so no memory op crosses either.
            if (q < 30)       asm volatile("s_waitcnt vmcnt(4)\n\ts_barrier" ::: "memory");
            else if (q == 30) asm volatile("s_waitcnt vmcnt(2)\n\ts_barrier" ::: "memory");
            else              asm volatile("s_waitcnt vmcnt(0)\n\ts_barrier" ::: "memory");
            // slot (q+3)&3's previous occupant (q-1) was packed before the
            // barrier above -> safe to re-fill now.
            if (q + 3 < 32) { GISSUE((q + 3) & 3); }
            if (tid < 560) {                       // PACK quarter q
                const char* rb = smb + (q & 3) * RAWQ + rbyte;
                float f[8];
#pragma unroll
                for (int e = 0; e < 8; ++e) f[e] = *(const float*)(rb + e * 2560);
                uint4 qq;
                qq.x = pk2(f[0], f[1]); qq.y = pk2(f[2], f[3]);
                qq.z = pk2(f[4], f[5]); qq.w = pk2(f[6], f[7]);
                *(uint4*)(smb + ((q >> 2) & 1) * FRAGSZ + fwb + ((sub ^ fxor) << 4)) = qq;
            }
        }
        // all PACK writes of this pair committed + visible, then MFMA
        asm volatile("s_waitcnt lgkmcnt(0)\n\ts_barrier" ::: "memory");
        const int P = (pr & 1) * FRAGSZ;
#pragma unroll
        for (int jj = 0; jj < 8; ++jj) {
            const bf16x8 bfr = *(const bf16x8*)(smb + P + boff[jj]);
            acc[jj] = __builtin_amdgcn_mfma_f32_16x16x32_bf16(abf[pr], bfr, acc[jj], 0, 0, 0);
        }
    }

    // ---- epilogue (R3/R4-verified): stage k-planes through LDS ----
    // C/D: n = lane&15 (q-pixel), m = oo*4 + r -> py=py0+oo, px=px0w+r
    const int psb = (py0 + oo) * PW + px0w;
#pragma unroll 1
    for (int pass = 0; pass < 2; ++pass) {
        const int kb = pass * KHALF;
        const int nk = pass ? (NT - KHALF) : KHALF;   // 85 / 84
        __syncthreads();
#pragma unroll
        for (int jj = 0; jj < 8; ++jj) {
            const int qi = qh * 8 + jj;
            const int di = 4 * (qi >> 2) + nhi - oo;
            const bool diok = (unsigned)di <= 12u;
            const int dib = di * 13;
#pragma unroll
            for (int r = 0; r < 4; ++r) {
                const int dj = 4 * (qi & 3) + nlo - r;
                const int k  = dib + dj;
                if (diok && (unsigned)dj <= 12u && k >= kb && k < kb + nk)
                    sm.outb[(k - kb) * OSTRIDE + psb + r] = acc[jj][r] * 0.0625f;
            }
        }
        __syncthreads();
        const int total4 = nk * 32;
        for (int i = tid; i < total4; i += 1024) {
            const int row = i >> 5, j = i & 31;
            const float4 val = *(const float4*)&sm.outb[row * OSTRIDE + j * 4];
            float* dst = out + (((size_t)(b * NT + kb + row) * HH + h0 + (j >> 2)) * WW
                                + w0 + (j & 3) * 4);
            *(float4*)dst = val;
        }
    }
}

extern "C" void kernel_launch(void* const* d_in, const int* in_sizes, int n_in,
                              void* d_out, int out_size, void* d_ws, size_t ws_size,
                              hipStream_t stream) {
    const float* zt  = (const float*)d_in[0];
    const float* zt1 = (const float*)d_in[1];
    float* out = (float*)d_out;
    float* ws  = (float*)d_ws;
    zero_ws<<<dim3(1), dim3(256), 0, stream>>>(ws);
    lc5<<<dim3(1024), dim3(1024), 0, stream>>>(zt, zt1, (const float*)ws, out);
}

// Round 6
// 210.503 us; speedup vs baseline: 1.0250x; 1.0250x over previous
//
#include <hip/hip_runtime.h>
#include <hip/hip_bf16.h>

// LocalCorrelation via MFMA, round 6: small blocks + TLP.
// out[b, di*13+dj, h, w] = (1/16) * sum_c zt[b,c,h,w] * zt1[b,c,h+di-6,w+dj-6]
// B=8 C=256 H=W=128, 13x13 taps, zero-padded.
//
// Block = 8x8 p-tile, 256 thr = 4 waves, wave = one 4x4 p-patch, 16 frags
// (mfma_f32_16x16x32_bf16, M=16 p-px, N=16 q-px, K=32ch), acc = 64 VGPR.
// q-region 20x20 px. zt1 staged in 4-ch quarters via global_load_lds into a
// ring of 3 raw slots (8KB each; rows of 24 floats from gx=w0-8); loads get
// ~3 phases of flight; constant vmcnt(4) wait (tail keeps the invariant with
// dummy zero-page loads). 49KB LDS + <=170 VGPR -> 3 blocks/CU: when one
// block stalls at a barrier, two others compute (the R4/R5 killer was
// 1-block/CU lockstep). PACK: 400 units (1px x 4ch): 4 b32 + 2 cvt_pk +
// 1 b64 write into bf16 pixel-major frag (oct-XOR swizzle; lane-constant
// across frags -> B-frag reads are one base + immediate offsets).
// A-operand global->reg once (anchored + vmcnt(0) before first DMA).
// Fragment geometry + epilogue verbatim from R2-R5 (HW-verified).

#define HH 128
#define WW 128
#define CCT 256
#define NT 169
#define CHPL (HH*WW)
#define RAWSLOT 8192
#define FRAGOFF (3*RAWSLOT)        // 24576
#define SMTOT (FRAGOFF + 25600)    // 50176 -> 3 blocks/CU
#define KHALF 85
#define OSTR 68

typedef __attribute__((ext_vector_type(8))) short bf16x8;
typedef __attribute__((ext_vector_type(4))) float f32x4;

union SMEM { char raw[SMTOT]; float outb[KHALF*OSTR]; };

static __device__ __forceinline__ unsigned pk2(float a, float b) {
    __hip_bfloat162 h = __float22bfloat162_rn(make_float2(a, b));
    union { __hip_bfloat162 h2; unsigned u; } c; c.h2 = h; return c.u;
}

__global__ void zero_ws(float* w) { if (threadIdx.x < 256) w[threadIdx.x] = 0.f; }

__global__ __launch_bounds__(256, 3)
void lc6(const float* __restrict__ zt, const float* __restrict__ zt1,
         const float* __restrict__ zpg, float* __restrict__ out) {
    __shared__ SMEM sm;
    char* smb = sm.raw;
    const int tid = threadIdx.x, lane = tid & 63, wid = tid >> 6;
    const int bid = blockIdx.x;
    const int b = bid & 7, t = bid >> 3;          // one batch per XCD
    const int h0 = (t >> 4) * 8, w0 = (t & 15) * 8;

    const int py0 = (wid >> 1) * 4, px0 = (wid & 1) * 4;
    const int nlo = lane & 3, nhi = (lane >> 2) & 3, oo = lane >> 4;

    // ---- DMA descriptors: 2 insts/wave/quarter (512 units, 480 real) ----
    const float* gq0; const float* gq1; int gadv0, gadv1;
    {
        const int u = wid * 64 + lane;
        const int ch = u / 120, rem = u % 120, qy = rem / 6, part = rem % 6;
        const int gy = h0 + qy - 6, gxs = w0 - 8 + part * 4;
        const bool val = (gy >= 0) && (gy < HH) && (gxs >= 0) && (gxs <= WW - 4);
        gq0 = val ? zt1 + ((size_t)(b*CCT + ch)*HH + gy)*WW + gxs : zpg + lane*4;
        gadv0 = val ? 4*CHPL : 0;
    }
    {
        const int u = 256 + wid * 64 + lane;      // 480..511 = pad -> zpg
        const int uu = (u < 480) ? u : 0;
        const int ch = uu / 120, rem = uu % 120, qy = rem / 6, part = rem % 6;
        const int gy = h0 + qy - 6, gxs = w0 - 8 + part * 4;
        const bool val = (u < 480) && (gy >= 0) && (gy < HH) && (gxs >= 0) && (gxs <= WW - 4);
        gq1 = val ? zt1 + ((size_t)(b*CCT + ch)*HH + gy)*WW + gxs : zpg + lane*4;
        gadv1 = val ? 4*CHPL : 0;
    }

#define GIS(SLOT, DUMMY) do {                                                  \
    const float* s0_ = (DUMMY) ? (zpg + lane*4) : gq0;                         \
    const float* s1_ = (DUMMY) ? (zpg + lane*4) : gq1;                         \
    __builtin_amdgcn_global_load_lds(                                          \
        (const __attribute__((address_space(1))) void*)s0_,                    \
        (__attribute__((address_space(3))) void*)(smb + (SLOT)*RAWSLOT + wid*1024), \
        16, 0, 0);                                                             \
    __builtin_amdgcn_global_load_lds(                                          \
        (const __attribute__((address_space(1))) void*)s1_,                    \
        (__attribute__((address_space(3))) void*)(smb + (SLOT)*RAWSLOT + 4096 + wid*1024), \
        16, 0, 0);                                                             \
    if (!(DUMMY)) { gq0 += gadv0; gq1 += gadv1; }                              \
} while (0)

    // ---- PACK descriptors (400 units: 1 px x 4 ch each) ----
    int prd[2], pfw[2], psw[2];
#pragma unroll
    for (int un = 0; un < 2; ++un) {
        const int n = un * 256 + tid;             // unit1 active only tid<144
        const int nn = (n < 400) ? n : 0;
        const int pqy = nn / 20, pqx = nn % 20;
        prd[un] = pqy * 96 + (pqx + 2) * 4;       // byte off in raw slot (+e*1920/ch)
        pfw[un] = FRAGOFF + nn * 64;
        psw[un] = (pqx + pqy) & 3;
    }

    // ---- B-frag base (swizzle term lane-constant across frags) ----
    const int qyL0 = py0 + nhi, qxL0 = px0 + nlo;
    const int boffb = FRAGOFF + (qyL0*20 + qxL0)*64 + ((oo ^ ((qxL0 + qyL0) & 3)) << 4);

    // ---- A-operand: global->reg once, pack to bf16 ----
    bf16x8 abf[8];
    {
        const float* ap = zt + ((size_t)(b*CCT + oo*8)*HH + (h0 + py0 + nhi))*WW
                             + (w0 + px0 + nlo);
#pragma unroll
        for (int pr = 0; pr < 8; ++pr) {
            float a8[8];
#pragma unroll
            for (int e = 0; e < 8; ++e) a8[e] = ap[(size_t)(pr*32 + e)*CHPL];
            union { unsigned u[4]; bf16x8 v; } au;
            au.u[0] = pk2(a8[0], a8[1]); au.u[1] = pk2(a8[2], a8[3]);
            au.u[2] = pk2(a8[4], a8[5]); au.u[3] = pk2(a8[6], a8[7]);
            abf[pr] = au.v;
        }
    }
    // anchor abf (forces loads to complete here; rule-17) then exact vmcnt=0
    asm volatile("" :: "v"(abf[0]), "v"(abf[1]), "v"(abf[2]), "v"(abf[3]),
                       "v"(abf[4]), "v"(abf[5]), "v"(abf[6]), "v"(abf[7]));
    asm volatile("s_waitcnt vmcnt(0)" ::: "memory");

    f32x4 acc[16];
#pragma unroll
    for (int j = 0; j < 16; ++j) acc[j] = (f32x4){0.f, 0.f, 0.f, 0.f};

    // prologue: quarters 0,1,2 in flight (6 insts)
    GIS(0, false); GIS(1, false); GIS(2, false);

#pragma unroll
    for (int pr = 0; pr < 8; ++pr) {
#pragma unroll
        for (int sub = 0; sub < 8; ++sub) {
            const int q = pr * 8 + sub;
            // wait quarter q landed (q+1,q+2 = 4 insts stay in flight), barrier
            asm volatile("s_waitcnt vmcnt(4)\n\ts_barrier" ::: "memory");
            {   // PACK quarter q: slot q%3 -> frag octet sub>>1, half sub&1
                const int so = (q % 3) * RAWSLOT;
#pragma unroll
                for (int un = 0; un < 2; ++un) {
                    if (un == 0 || tid < 144) {
                        const char* rb = smb + so + prd[un];
                        const float f0 = *(const float*)(rb);
                        const float f1 = *(const float*)(rb + 1920);
                        const float f2 = *(const float*)(rb + 3840);
                        const float f3 = *(const float*)(rb + 5760);
                        uint2 wv; wv.x = pk2(f0, f1); wv.y = pk2(f2, f3);
                        *(uint2*)(smb + pfw[un] + ((((sub >> 1)) ^ psw[un]) << 4)
                                  + (sub & 1) * 8) = wv;
                    }
                }
            }
            // all pack reads/writes of q done across waves -> slot q%3 free
            asm volatile("s_waitcnt lgkmcnt(0)\n\ts_barrier" ::: "memory");
            if (q + 3 < 64) { GIS(q % 3, false); }
            else            { GIS(q % 3, true);  }   // dummy keeps vmcnt invariant
        }
        // MFMA chunk pr (frag complete as of last post-pack barrier)
        {
            const char* fb = smb + boffb;
#pragma unroll
            for (int jj = 0; jj < 16; ++jj) {
                const bf16x8 bfr = *(const bf16x8*)(fb + (jj >> 2)*5120 + (jj & 3)*256);
                acc[jj] = __builtin_amdgcn_mfma_f32_16x16x32_bf16(abf[pr], bfr, acc[jj], 0, 0, 0);
            }
        }
    }

    // ---- epilogue (R3-R5-verified): stage k-planes through LDS ----
    // C/D: n = lane&15 (q-px), m = oo*4 + r -> py = py0+oo, px = px0+r
    const int psb = (py0 + oo) * 8 + px0;
#pragma unroll 1
    for (int pass = 0; pass < 2; ++pass) {
        const int kb = pass * KHALF;
        const int nk = pass ? (NT - KHALF) : KHALF;   // 85 / 84
        __syncthreads();   // also drains tail dummy loads (pass 0)
#pragma unroll
        for (int jj = 0; jj < 16; ++jj) {
            const int di = 4*(jj >> 2) + nhi - oo;
            const bool diok = (unsigned)di <= 12u;
            const int dib = di * 13;
#pragma unroll
            for (int r = 0; r < 4; ++r) {
                const int dj = 4*(jj & 3) + nlo - r;
                const int k  = dib + dj;
                if (diok && (unsigned)dj <= 12u && k >= kb && k < kb + nk)
                    sm.outb[(k - kb)*OSTR + psb + r] = acc[jj][r] * 0.0625f;
            }
        }
        __syncthreads();
        const int total4 = nk * 16;
        for (int i = tid; i < total4; i += 256) {
            const int row = i >> 4, j = i & 15;
            const float4 val = *(const float4*)&sm.outb[row*OSTR + j*4];
            float* dst = out + (((size_t)(b*NT + kb + row)*HH + h0 + (j >> 1))*WW
                                + w0 + (j & 1)*4);
            *(float4*)dst = val;
        }
    }
}

extern "C" void kernel_launch(void* const* d_in, const int* in_sizes, int n_in,
                              void* d_out, int out_size, void* d_ws, size_t ws_size,
                              hipStream_t stream) {
    const float* zt  = (const float*)d_in[0];
    const float* zt1 = (const float*)d_in[1];
    float* out = (float*)d_out;
    float* ws  = (float*)d_ws;
    zero_ws<<<dim3(1), dim3(256), 0, stream>>>(ws);
    lc6<<<dim3(2048), dim3(256), 0, stream>>>(zt, zt1, (const float*)ws, out);
}